// Round 6
// baseline (97399.988 us; speedup 1.0000x reference)
//
#include <hip/hip_runtime.h>
#include <math.h>

// ---- static dims ----
#define B8      8
#define LSEQ    512
#define NWG     256
#define TPB     512
#define RELK    97
#define BI      148
#define FSTR    16        // barrier flag stride (ints) = 64B
#define LDSF    39040     // floats: sA 4160 | sRed 64 | wA 18432 | w1 2048 | w2 2048 | wxi 12288
#define LDSB    (LDSF*4)
#define NC      8         // broadcast replication factor
#define RCPY    32768     // reads copy stride (floats)

__device__ __forceinline__ float sigf(float x){
  return (x >= 0.f) ? 1.f/(1.f + expf(-x)) : expf(x)/(1.f + expf(x));
}
__device__ __forceinline__ float spf(float x){ // softplus, stable
  return (x > 0.f) ? x + log1pf(expf(-x)) : log1pf(expf(x));
}

// agent-scope (L2-bypassing, L3-coherent) element transfer for cross-wg data
__device__ __forceinline__ float agld(const float* p){
  return __hip_atomic_load(p, __ATOMIC_RELAXED, __HIP_MEMORY_SCOPE_AGENT);
}
__device__ __forceinline__ void agst(float* p, float v){
  __hip_atomic_store(p, v, __ATOMIC_RELAXED, __HIP_MEMORY_SCOPE_AGENT);
}

// ---------------------------------------------------------------- sent gather
__global__ __launch_bounds__(256)
void k_sent(const int* __restrict__ cidx, const int* __restrict__ pos,
            const int* __restrict__ ner, const float* __restrict__ wemb,
            const float* __restrict__ eemb, const float* __restrict__ nemb,
            float* __restrict__ sent)
{
  int flat = blockIdx.x*256 + threadIdx.x;
  if (flat >= B8*LSEQ*140) return;
  int d = flat % 140; int bl = flat / 140;
  float v;
  if (d < 100)      v = wemb[(size_t)cidx[bl]*100 + d];
  else if (d < 120) v = eemb[(size_t)pos[bl]*20 + (d-100)];
  else              v = nemb[(size_t)ner[bl]*20 + (d-120)];
  sent[flat] = v;
}

// ------------------------------------------- weight transpose/concat (once)
__global__ __launch_bounds__(256)
void k_tr(const float* __restrict__ A, const float* __restrict__ Bsrc,
          int N, int K1a, int K1b, int K2, long long total, float* __restrict__ T)
{
  long long i = (long long)blockIdx.x*256 + threadIdx.x;
  if (i >= total) return;
  int k = (int)(i % K2);
  long long c = i / K2;
  float v = 0.f;
  if (k < K1a)            v = A[(size_t)k*N + c];
  else if (k < K1a+K1b)   v = Bsrc[(size_t)(k-K1a)*N + c];
  T[i] = v;
}

// ---------------------------------------------------------- global barrier
// fence-free: vmcnt-drain release + agent atomics. wg0 gathers 256 flags
// (1 poller/line), then posts a DEDICATED gen line per wg (zero sharing).
__device__ __forceinline__ void gbar(int* flags, int* genrep, int seq){
  __syncthreads();
  const int tid = threadIdx.x;
  const int bid = blockIdx.x;
  if (tid == 0){
    asm volatile("s_waitcnt vmcnt(0)" ::: "memory");
    __hip_atomic_store(&flags[bid*FSTR], seq, __ATOMIC_RELAXED, __HIP_MEMORY_SCOPE_AGENT);
  }
  if (bid == 0){
    if (tid < NWG){
      while (__hip_atomic_load(&flags[tid*FSTR], __ATOMIC_RELAXED, __HIP_MEMORY_SCOPE_AGENT) < seq)
        __builtin_amdgcn_s_sleep(1);
    }
    __syncthreads();
    if (tid < NWG)
      __hip_atomic_store(&genrep[tid*FSTR], seq, __ATOMIC_RELAXED, __HIP_MEMORY_SCOPE_AGENT);
  } else if (tid == 0){
    while (__hip_atomic_load(&genrep[bid*FSTR], __ATOMIC_RELAXED, __HIP_MEMORY_SCOPE_AGENT) < seq)
      __builtin_amdgcn_s_sleep(1);
  }
  __syncthreads();
}

// ------------------------------------- per-sample DNC memory addressing phase
// scratch = 3776 floats, overlays the sA/sRed region (dead during phase E)
__device__ void mem_phase(float* lds, const float* __restrict__ xi,
                          float* __restrict__ M, float* u_g, float* ww_g,
                          float* p_g, float* wr_g, float* L_g, float* rout0)
{
  const int tid = threadIdx.x;
  float* mL  = lds;          // [32][32]
  float* mwr = lds+1024;     // [8][32]
  float* mwrn= lds+1280;
  float* mcr = lds+1536;
  float* mfw = lds+1792;
  float* mbw = lds+2048;
  float* PSI = lds+2304;
  float* UU  = lds+2336;
  float* US  = lds+2368;
  float* AA  = lds+2400;
  float* CW  = lds+2432;
  float* WWN = lds+2464;
  float* WWO = lds+2496;
  float* PP  = lds+2528;
  int*   mord= (int*)(lds+2560);   // 32 ints
  float* mh  = lds+2592;           // rb[0..7] sf[8..15] sb[16..23] fg[24..31]
  float* mpi = lds+2656;           // [8][3]
  float* msc = lds+2688;           // 64 scratch scalars
  float* q1  = lds+2752;           // 512
  float* q2  = lds+3264;           // 512

  // ---- interface scalars / state load ----
  if (tid < 8){
    mh[tid]    = 1.f + spf(agld(&xi[4096+tid]));     // read strengths
    mh[8+tid]  = 1.f + spf(agld(&xi[10283+tid]));    // sf
    mh[16+tid] = 1.f + spf(agld(&xi[10291+tid]));    // sb
    mh[24+tid] = sigf(agld(&xi[5641+tid]));          // free gates
    float e0=agld(&xi[5651+3*tid]), e1=agld(&xi[5652+3*tid]), e2=agld(&xi[5653+3*tid]);
    float mx=fmaxf(e0,fmaxf(e1,e2));
    float x0=expf(e0-mx), x1=expf(e1-mx), x2=expf(e2-mx);
    float inv=1.f/(x0+x1+x2);
    mpi[tid*3]=x0*inv; mpi[tid*3+1]=x1*inv; mpi[tid*3+2]=x2*inv;
  }
  if (tid==0){ msc[0]=1.f+spf(agld(&xi[4616])); msc[1]=sigf(agld(&xi[5649])); msc[2]=sigf(agld(&xi[5650])); }
  if (tid<32){ UU[tid]=u_g[tid]; WWO[tid]=ww_g[tid]; PP[tid]=p_g[tid]; }
  if (tid<256) mwr[tid]=wr_g[tid];
  mL[tid]=L_g[tid]; mL[tid+512]=L_g[tid+512];
  { float wm = 0.1f+0.9f*sigf(agld(&xi[5675+tid])); q1[tid]=agld(&xi[4104+tid])*wm; q2[tid]=wm; }
  __syncthreads();

  // psi, usage
  if (tid<32){
    float psi=1.f;
    #pragma unroll
    for (int r=0;r<8;r++) psi *= (1.f - mh[24+r]*mwr[r*32+tid]);
    PSI[tid]=psi;
    float uo=UU[tid], wo=WWO[tid];
    UU[tid]=(uo+wo-uo*wo)*psi;
  }
  __syncthreads();
  // stable ascending argsort of u
  if (tid<32){
    float un=UU[tid]; int rank=0;
    for (int m=0;m<32;m++){ float um=UU[m]; rank += (um<un)||(um==un && m<tid); }
    mord[rank]=tid;
  }
  __syncthreads();
  if (tid<32) US[tid]=UU[mord[tid]];
  __syncthreads();
  if (tid==0){ float cp=1.f; for (int j=0;j<32;j++){ AA[mord[j]]=(1.f-US[j])*cp; cp*=US[j]; } }
  __syncthreads();

  // write content weighting cw (OLD M)
  { float q=q1[tid]*q1[tid];
    for (int o=32;o;o>>=1) q += __shfl_down(q,o,64);
    if ((tid&63)==0) msc[8+(tid>>6)]=q; }
  __syncthreads();
  if (tid==0){ float q=0.f; for (int i=0;i<8;i++) q+=msc[8+i]; msc[3]=sqrtf(q); }
  __syncthreads();
  { int n=tid>>4, wsub=tid&15;
    float d=0.f,q=0.f;
    for (int i=0;i<32;i++){ int w=wsub+16*i; float m=M[(size_t)n*512+w]; float t2=m*q2[w]; d+=q1[w]*t2; q+=t2*t2; }
    for (int o=8;o;o>>=1){ d+=__shfl_down(d,o,16); q+=__shfl_down(q,o,16); }
    if (wsub==0){ float cs=d/(msc[3]*sqrtf(q)+1e-6f); CW[n]=msc[0]*cs; } }
  __syncthreads();
  if (tid==0){ float mx=-1e30f; for(int n=0;n<32;n++) mx=fmaxf(mx,CW[n]); msc[4]=mx; }
  __syncthreads();
  if (tid<32) CW[tid]=expf(CW[tid]-msc[4]);
  __syncthreads();
  if (tid==0){ float sm=0.f; for(int n=0;n<32;n++) sm+=CW[n]; msc[5]=1.f/sm; }
  __syncthreads();
  if (tid<32) CW[tid]*=msc[5];
  __syncthreads();
  // write weights
  if (tid<32) WWN[tid]=msc[2]*(msc[1]*AA[tid]+(1.f-msc[1])*CW[tid]);
  __syncthreads();
  // M dealloc + erase/write (w index == tid)
  { float er=sigf(agld(&xi[4617+tid])); float wv=agld(&xi[5129+tid]);
    for (int n=0;n<32;n++){ size_t idx=(size_t)n*512+tid; float m=M[idx];
      M[idx]=m*PSI[n]*(1.f-WWN[n]*er)+WWN[n]*wv; } }
  __syncthreads();
  // link matrix (OLD p), then precedence
  for (int ii=0;ii<2;ii++){ int f=tid+512*ii; int i=f>>5, j=f&31;
    float nl=(1.f-WWN[i]-WWN[j])*mL[f]+WWN[i]*PP[j];
    mL[f]=(i==j)?0.f:nl; }
  __syncthreads();
  if (tid==0){ float sw=0.f; for(int n=0;n<32;n++) sw+=WWN[n]; msc[6]=sw; }
  __syncthreads();
  if (tid<32) PP[tid]=(1.f-msc[6])*PP[tid]+WWN[tid];
  __syncthreads();
  // fw/bw sharpened (OLD wr)
  { int r=(tid>>5)&7, i=tid&31; bool isB=(tid>=256);
    float accv=0.f;
    if (!isB){ for (int j=0;j<32;j++) accv += mL[i*32+j]*mwr[r*32+j]; }
    else     { for (int j=0;j<32;j++) accv += mL[j*32+i]*mwr[r*32+j]; }
    float sp = isB? mh[16+r] : mh[8+r];
    float e = expf(sp*logf(accv+1e-6f));
    if (!isB) mfw[r*32+i]=e; else mbw[r*32+i]=e; }
  __syncthreads();
  if (tid<16){ int r=tid&7; float sm=0.f;
    if (tid<8){ for(int n=0;n<32;n++) sm+=mfw[r*32+n]; msc[16+r]=1.f/sm; }
    else      { for(int n=0;n<32;n++) sm+=mbw[r*32+n]; msc[24+r]=1.f/sm; } }
  __syncthreads();
  { int r=(tid>>5)&7, i=tid&31; bool isB=(tid>=256);
    if (!isB) mfw[r*32+i]*=msc[16+r]; else mbw[r*32+i]*=msc[24+r]; }
  __syncthreads();
  // read content weighting cr (NEW M), one head at a time (q1/q2 reused)
  for (int r=0;r<8;r++){
    { float rm=0.1f+0.9f*sigf(agld(&xi[6187+r*512+tid]));
      q1[tid]=agld(&xi[r*512+tid])*rm; q2[tid]=rm; }
    __syncthreads();
    { float q=q1[tid]*q1[tid];
      for (int o=32;o;o>>=1) q+=__shfl_down(q,o,64);
      if ((tid&63)==0) msc[8+(tid>>6)]=q; }
    __syncthreads();
    if (tid==0){ float qq=0.f; for(int i=0;i<8;i++) qq+=msc[8+i]; msc[32]=sqrtf(qq); }
    __syncthreads();
    { int n=tid>>4, wsub=tid&15;
      float d=0.f,q=0.f;
      for (int i=0;i<32;i++){ int w=wsub+16*i; float m=M[(size_t)n*512+w]; float t2=m*q2[w]; d+=q1[w]*t2; q+=t2*t2; }
      for (int o=8;o;o>>=1){ d+=__shfl_down(d,o,16); q+=__shfl_down(q,o,16); }
      if (wsub==0){ float cs=d/(msc[32]*sqrtf(q)+1e-6f); mcr[r*32+n]=mh[r]*cs; } }
    __syncthreads();
  }
  if (tid<8){ int r=tid; float mx=-1e30f;
    for (int n=0;n<32;n++) mx=fmaxf(mx,mcr[r*32+n]);
    float sm=0.f;
    for (int n=0;n<32;n++){ float e=expf(mcr[r*32+n]-mx); mcr[r*32+n]=e; sm+=e; }
    float inv=1.f/sm;
    for (int n=0;n<32;n++) mcr[r*32+n]*=inv; }
  __syncthreads();
  // new read weights
  if (tid<256){ int r=tid>>5, n=tid&31;
    float v=mpi[r*3]*mbw[r*32+n]+mpi[r*3+1]*mcr[r*32+n]+mpi[r*3+2]*mfw[r*32+n];
    mwrn[tid]=v; wr_g[tid]=v; }
  __syncthreads();
  // reads = wr_new @ M_new  -> write ALL NC copies (contention spreading)
  { int r=tid>>6, wsub=tid&63;
    for (int i2=0;i2<8;i2++){ int w=wsub+64*i2;
      float accv=0.f;
      for (int n=0;n<32;n++) accv+=mwrn[r*32+n]*M[(size_t)n*512+w];
      #pragma unroll
      for (int c2=0;c2<NC;c2++) agst(&rout0[(size_t)c2*RCPY + r*512+w], accv); } }
  // state writeback (private -> plain)
  if (tid<32){ u_g[tid]=UU[tid]; ww_g[tid]=WWN[tid]; p_g[tid]=PP[tid]; }
  L_g[tid]=mL[tid]; L_g[tid+512]=mL[tid+512];
}

// ---------------------------------------------- persistent whole-recurrence
// Weights LDS-resident; broadcast buffers replicated x8; staggered addressing.
__global__ __launch_bounds__(TPB, 1)
void dnc_persist(
  const float* __restrict__ sent,
  const float* __restrict__ WAg, const float* __restrict__ b0,
  const float* __restrict__ W1g, const float* __restrict__ b1,
  const float* __restrict__ W2g, const float* __restrict__ b2,
  const float* __restrict__ WXIg,const float* __restrict__ bxi,
  const float* __restrict__ WY,  const float* __restrict__ bout,
  float* __restrict__ Hh, float* __restrict__ yh, float* __restrict__ Hy,
  float* __restrict__ reads2,
  float* __restrict__ h0g, float* __restrict__ h1g, float* __restrict__ h2g,
  float* __restrict__ c0g, float* __restrict__ c1g, float* __restrict__ c2g,
  float* __restrict__ z0g, float* __restrict__ z1g, float* __restrict__ z2g,
  float* __restrict__ xig,
  float* __restrict__ Mb, float* __restrict__ ug, float* __restrict__ wwg,
  float* __restrict__ pg, float* __restrict__ wrg, float* __restrict__ Lg,
  int* flags, int* genrep)
{
  extern __shared__ float lds[];
  float* sA   = lds;                 // 8 x 520
  float* sRed = lds + 4160;          // 64
  float* wA   = lds + 4224;          // 4 cols x 4608
  float* w1l  = lds + 22656;         // 4 cols x 512
  float* w2l  = lds + 24704;         // 4 cols x 512
  float* wxl  = lds + 26752;         // 48 cols x 256
  const int wg  = blockIdx.x;
  const int tid = threadIdx.x;
  const int cq = tid >> 7, kq = tid & 127;   // z-gemm layout (4 cols/wg)
  const int xc = tid >> 6, xk = tid & 63;    // xi layout (48 cols/wg)
  const int cp = wg >> 5;                    // broadcast copy id
  const int kk = (tid + (wg<<4)) & 511;      // staggered chunk lane
  const int jj = (tid + (wg<<4)) & 255;      // staggered gate lane
  const int ptid = kk;                       // staggered y-gemm lane
  int seq = 0;

  // ---------------- one-time: weights -> LDS ----------------
  for (int f=tid; f<18432; f+=TPB) wA[f]  = WAg[(size_t)wg*18432 + f];
  for (int f=tid; f<2048;  f+=TPB) w1l[f] = W1g[(size_t)wg*2048  + f];
  for (int f=tid; f<2048;  f+=TPB) w2l[f] = W2g[(size_t)wg*2048  + f];
  for (int f=tid; f<12288; f+=TPB){
    int cl = f>>8, k = f&255; int col = wg*48 + cl;
    wxl[f] = (col < 10299) ? WXIg[(size_t)col*256 + k] : 0.f;
  }
  const bool isy = (wg >= 8 && wg < 148);
  const bool iscw = (wg >= 8 && wg < 16);    // cell-state writer, copy wg-8
  const int  gcw = wg - 8;
  const float* wcolY = WY + (size_t)(isy ? (wg-8) : 0)*4352;
  __syncthreads();

  #pragma unroll 1
  for (int t=0; t<LSEQ; t++){
    const int rp = t&1, wp = rp^1, pprev = (t+1)&1;
    const float* readsPrev = reads2 + ((size_t)pprev*NC + cp)*RCPY;
    const float* h0p = h0g + ((size_t)pprev*NC + cp)*2048;
    const float* h1p = h1g + ((size_t)pprev*NC + cp)*2048;
    const float* h2p = h2g + ((size_t)pprev*NC + cp)*2048;

    // ================= phase A: z0 gemm, staggered chunks ================
    {
      float acc[8] = {0,0,0,0,0,0,0,0};
      float av[8];
      int ch = wg % 9;
      {
        int kg = ch*512 + kk;
        #pragma unroll
        for (int s=0;s<8;s++){
          float v;
          if (kg < 140)       v = sent[((size_t)s*512 + t)*140 + kg];
          else if (kg < 4236) v = agld(&readsPrev[s*4096 + kg - 140]);
          else if (kg < 4492) v = agld(&h0p[s*256 + (kg-4236)]);
          else                v = 0.f;
          av[s]=v;
        }
      }
      #pragma unroll 1
      for (int ci=0; ci<9; ci++){
        __syncthreads();
        #pragma unroll
        for (int s=0;s<8;s++) sA[s*520 + kk] = av[s];
        __syncthreads();
        const int cur = ch;
        ch = (ch+1 == 9) ? 0 : ch+1;
        if (ci < 8){
          int kg = ch*512 + kk;
          #pragma unroll
          for (int s=0;s<8;s++){
            float v;
            if (kg < 140)       v = sent[((size_t)s*512 + t)*140 + kg];
            else if (kg < 4236) v = agld(&readsPrev[s*4096 + kg - 140]);
            else if (kg < 4492) v = agld(&h0p[s*256 + (kg-4236)]);
            else                v = 0.f;
            av[s]=v;
          }
        }
        float4 wv = *reinterpret_cast<const float4*>(&wA[cq*4608 + cur*512 + (kq<<2)]);
        #pragma unroll
        for (int s=0;s<8;s++){
          float4 a = *reinterpret_cast<const float4*>(&sA[s*520 + (kq<<2)]);
          acc[s] += a.x*wv.x + a.y*wv.y + a.z*wv.z + a.w*wv.w;
        }
      }
      #pragma unroll
      for (int o=32;o;o>>=1)
        #pragma unroll
        for (int s=0;s<8;s++) acc[s]+=__shfl_down(acc[s],o,64);
      if ((tid&63)==0){ int wv2=tid>>6;
        #pragma unroll
        for (int s=0;s<8;s++) sRed[wv2*8+s]=acc[s]; }
      __syncthreads();
      if (tid<32){ int c=tid>>3, s=tid&7;
        float v = sRed[c*16+s] + sRed[c*16+8+s] + b0[wg*4+c];
        #pragma unroll
        for (int c2=0;c2<NC;c2++) agst(&z0g[(size_t)c2*8192 + s*1024 + wg*4 + c], v); }
    }
    gbar(flags,genrep,++seq);

    // ================= phase B: cell0 + z1 gemm =========================
    {
      const float* z0c = z0g + (size_t)cp*8192;
      float4 w1v = *reinterpret_cast<const float4*>(&w1l[cq*512 + (kq<<2)]);
      if (tid<256){
        #pragma unroll
        for (int s=0;s<8;s++){
          float zi=agld(&z0c[s*1024+jj]), zf=agld(&z0c[s*1024+256+jj]);
          float zg=agld(&z0c[s*1024+512+jj]), zo=agld(&z0c[s*1024+768+jj]);
          float cold=agld(&c0g[((size_t)rp*NC+cp)*2048+s*256+jj]);
          float cn=sigf(zf)*cold+sigf(zi)*tanhf(zg);
          float h=sigf(zo)*tanhf(cn);
          sA[s*520+jj]=h;
          if (iscw){ agst(&c0g[((size_t)wp*NC+gcw)*2048+s*256+jj],cn);
                     agst(&h0g[((size_t)rp*NC+gcw)*2048+s*256+jj],h); }
        }
      } else {
        int j2=(tid-256 + (wg<<4)) & 255;
        #pragma unroll
        for (int s=0;s<8;s++) sA[s*520+256+j2]=agld(&h1p[s*256+j2]);
      }
      __syncthreads();
      float acc[8]={0,0,0,0,0,0,0,0};
      #pragma unroll
      for (int s=0;s<8;s++){
        float4 a=*reinterpret_cast<const float4*>(&sA[s*520+(kq<<2)]);
        acc[s]+=a.x*w1v.x+a.y*w1v.y+a.z*w1v.z+a.w*w1v.w;
      }
      #pragma unroll
      for (int o=32;o;o>>=1)
        #pragma unroll
        for (int s=0;s<8;s++) acc[s]+=__shfl_down(acc[s],o,64);
      if ((tid&63)==0){ int wv2=tid>>6;
        #pragma unroll
        for (int s=0;s<8;s++) sRed[wv2*8+s]=acc[s]; }
      __syncthreads();
      if (tid<32){ int c=tid>>3, s=tid&7;
        float v = sRed[c*16+s] + sRed[c*16+8+s] + b1[wg*4+c];
        #pragma unroll
        for (int c2=0;c2<NC;c2++) agst(&z1g[(size_t)c2*8192 + s*1024 + wg*4 + c], v); }
    }
    gbar(flags,genrep,++seq);

    // ================= phase C: cell1 + z2 gemm =========================
    {
      const float* z1c = z1g + (size_t)cp*8192;
      float4 w2v = *reinterpret_cast<const float4*>(&w2l[cq*512 + (kq<<2)]);
      if (tid<256){
        #pragma unroll
        for (int s=0;s<8;s++){
          float zi=agld(&z1c[s*1024+jj]), zf=agld(&z1c[s*1024+256+jj]);
          float zg=agld(&z1c[s*1024+512+jj]), zo=agld(&z1c[s*1024+768+jj]);
          float cold=agld(&c1g[((size_t)rp*NC+cp)*2048+s*256+jj]);
          float cn=sigf(zf)*cold+sigf(zi)*tanhf(zg);
          float h=sigf(zo)*tanhf(cn);
          sA[s*520+jj]=h;
          if (iscw){ agst(&c1g[((size_t)wp*NC+gcw)*2048+s*256+jj],cn);
                     agst(&h1g[((size_t)rp*NC+gcw)*2048+s*256+jj],h); }
        }
      } else {
        int j2=(tid-256 + (wg<<4)) & 255;
        #pragma unroll
        for (int s=0;s<8;s++) sA[s*520+256+j2]=agld(&h2p[s*256+j2]);
      }
      __syncthreads();
      float acc[8]={0,0,0,0,0,0,0,0};
      #pragma unroll
      for (int s=0;s<8;s++){
        float4 a=*reinterpret_cast<const float4*>(&sA[s*520+(kq<<2)]);
        acc[s]+=a.x*w2v.x+a.y*w2v.y+a.z*w2v.z+a.w*w2v.w;
      }
      #pragma unroll
      for (int o=32;o;o>>=1)
        #pragma unroll
        for (int s=0;s<8;s++) acc[s]+=__shfl_down(acc[s],o,64);
      if ((tid&63)==0){ int wv2=tid>>6;
        #pragma unroll
        for (int s=0;s<8;s++) sRed[wv2*8+s]=acc[s]; }
      __syncthreads();
      if (tid<32){ int c=tid>>3, s=tid&7;
        float v = sRed[c*16+s] + sRed[c*16+8+s] + b2[wg*4+c];
        #pragma unroll
        for (int c2=0;c2<NC;c2++) agst(&z2g[(size_t)c2*8192 + s*1024 + wg*4 + c], v); }
    }
    gbar(flags,genrep,++seq);

    // ================= phase D: cell2 + xi gemm =========================
    {
      const float* z2c = z2g + (size_t)cp*8192;
      if (tid<256){
        #pragma unroll
        for (int s=0;s<8;s++){
          float zi=agld(&z2c[s*1024+jj]), zf=agld(&z2c[s*1024+256+jj]);
          float zg=agld(&z2c[s*1024+512+jj]), zo=agld(&z2c[s*1024+768+jj]);
          float cold=agld(&c2g[((size_t)rp*NC+cp)*2048+s*256+jj]);
          float cn=sigf(zf)*cold+sigf(zi)*tanhf(zg);
          float h2=sigf(zo)*tanhf(cn);
          float hc=fminf(fmaxf(h2,-20.f),20.f);
          sA[s*520+jj]=hc;
          if (iscw){ agst(&c2g[((size_t)wp*NC+gcw)*2048+s*256+jj],cn);
                     agst(&h2g[((size_t)rp*NC+gcw)*2048+s*256+jj],h2);
                     agst(&Hy[((size_t)rp*NC+gcw)*2048+s*256+jj],hc);
                     if (wg==8) Hh[((size_t)t*8+s)*256+jj]=hc; }
        }
      }
      __syncthreads();
      float accx[6][8];
      #pragma unroll
      for (int cc=0;cc<6;cc++)
        #pragma unroll
        for (int s=0;s<8;s++) accx[cc][s]=0.f;
      #pragma unroll
      for (int s=0;s<8;s++){
        float4 a = *reinterpret_cast<const float4*>(&sA[s*520 + (xk<<2)]);
        #pragma unroll
        for (int cc=0;cc<6;cc++){
          float4 wv = *reinterpret_cast<const float4*>(&wxl[(xc*6+cc)*256 + (xk<<2)]);
          accx[cc][s] += a.x*wv.x + a.y*wv.y + a.z*wv.z + a.w*wv.w;
        }
      }
      #pragma unroll
      for (int o=32;o;o>>=1)
        #pragma unroll
        for (int cc=0;cc<6;cc++)
          #pragma unroll
          for (int s=0;s<8;s++) accx[cc][s]+=__shfl_down(accx[cc][s],o,64);
      if ((tid&63)==0){
        #pragma unroll
        for (int cc=0;cc<6;cc++){
          int col = wg*48 + xc*6 + cc;
          if (col < 10299){
            #pragma unroll
            for (int s=0;s<8;s++) agst(&xig[(size_t)s*10299+col], accx[cc][s]+bxi[col]);
          }
        }
      }
    }
    gbar(flags,genrep,++seq);

    // ================= phase E: memory update (wg<8) + y(t-1) ==========
    if (wg < 8){
      mem_phase(lds, xig + (size_t)wg*10299, Mb + (size_t)wg*16384,
                ug+wg*32, wwg+wg*32, pg+wg*32, wrg+wg*256, Lg+wg*1024,
                reads2 + (size_t)rp*NC*RCPY + wg*4096);
    } else if (isy && t > 0){
      int ty = t-1;
      const float* rdp = reads2 + ((size_t)(ty&1)*NC + cp)*RCPY;
      const float* Hyp = Hy + ((size_t)(ty&1)*NC + cp)*2048;
      float wy[9];
      #pragma unroll
      for (int ch=0;ch<9;ch++){ int k=ch*512+ptid; wy[ch]=(k<4352)? wcolY[k] : 0.f; }
      float acy[8]={0,0,0,0,0,0,0,0};
      #pragma unroll
      for (int ci=0;ci<9;ci++){
        int ch = (ci + wg) % 9;
        int kg = ch*512+ptid;
        #pragma unroll
        for (int s=0;s<8;s++){
          float a;
          if (kg<256)       a=agld(&Hyp[s*256+kg]);
          else if (kg<4352) a=agld(&rdp[s*4096+kg-256]);
          else              a=0.f;
          acy[s]+=a*wy[ch];
        }
      }
      #pragma unroll
      for (int o=32;o;o>>=1)
        #pragma unroll
        for (int s=0;s<8;s++) acy[s]+=__shfl_down(acy[s],o,64);
      if ((tid&63)==0){ int wv2=tid>>6;
        #pragma unroll
        for (int s=0;s<8;s++) sRed[wv2*8+s]=acy[s]; }
      __syncthreads();
      if (tid<8){ float v=0.f;
        #pragma unroll
        for (int w=0;w<8;w++) v+=sRed[w*8+tid];
        yh[((size_t)tid*512+ty)*140+(wg-8)]=v+bout[wg-8]; }
    }
    gbar(flags,genrep,++seq);
  }

  // ---------------- final y(511) ----------------
  if (isy){
    int ty = 511;
    const float* rdp = reads2 + ((size_t)(ty&1)*NC + cp)*RCPY;
    const float* Hyp = Hy + ((size_t)(ty&1)*NC + cp)*2048;
    float wy[9];
    #pragma unroll
    for (int ch=0;ch<9;ch++){ int k=ch*512+ptid; wy[ch]=(k<4352)? wcolY[k] : 0.f; }
    float acy[8]={0,0,0,0,0,0,0,0};
    #pragma unroll
    for (int ci=0;ci<9;ci++){
      int ch = (ci + wg) % 9;
      int kg = ch*512+ptid;
      #pragma unroll
      for (int s=0;s<8;s++){
        float a;
        if (kg<256)       a=agld(&Hyp[s*256+kg]);
        else if (kg<4352) a=agld(&rdp[s*4096+kg-256]);
        else              a=0.f;
        acy[s]+=a*wy[ch];
      }
    }
    #pragma unroll
    for (int o=32;o;o>>=1)
      #pragma unroll
      for (int s=0;s<8;s++) acy[s]+=__shfl_down(acy[s],o,64);
    if ((tid&63)==0){ int wv2=tid>>6;
      #pragma unroll
      for (int s=0;s<8;s++) sRed[wv2*8+s]=acy[s]; }
    __syncthreads();
    if (tid<8){ float v=0.f;
      #pragma unroll
      for (int w=0;w<8;w++) v+=sRed[w*8+tid];
      yh[((size_t)tid*512+ty)*140+(wg-8)]=v+bout[wg-8]; }
  }
}

// ---------------------------------------- generic 16-row tiled gemm (lda==K)
__global__ __launch_bounds__(256)
void gemm16(int M, int N, int K,
            const float* __restrict__ A, long long sAb, int lda,
            const float* __restrict__ Bm, long long sBb, int ldb,
            float* __restrict__ C, long long sCb, int ldc,
            const float* __restrict__ bias, int relu)
{
  __shared__ float sAh[16*512];
  const int tid = threadIdx.x;
  const float* Ab = A + (size_t)blockIdx.y*sAb;
  const float* Bb = Bm + (size_t)blockIdx.y*sBb;
  float* Cb = C + (size_t)blockIdx.y*sCb;
  const int m0 = blockIdx.x*16;
  const int tot = 16*K;
  for (int f = tid; f < tot; f += 256) sAh[f] = Ab[(size_t)m0*lda + f]; // lda==K
  __syncthreads();
  int c = (tid & 63)*4; int rg = tid >> 6;
  if (c >= N) return;
  float acc[4][4] = {};
  for (int k=0;k<K;k++){
    float4 bv = *reinterpret_cast<const float4*>(Bb + (size_t)k*ldb + c);
    #pragma unroll
    for (int rr=0;rr<4;rr++){
      float a = sAh[(rg*4+rr)*K + k];
      acc[rr][0] += a*bv.x; acc[rr][1] += a*bv.y; acc[rr][2] += a*bv.z; acc[rr][3] += a*bv.w;
    }
  }
  for (int rr=0;rr<4;rr++){
    int m = m0 + rg*4 + rr;
    #pragma unroll
    for (int e=0;e<4;e++){
      float v = acc[rr][e] + (bias ? bias[c+e] : 0.f);
      if (relu) v = fmaxf(v, 0.f);
      Cb[(size_t)m*ldc + c + e] = v;
    }
  }
}

// ------------------------------------------------------------ bilinear head
__global__ __launch_bounds__(256)
void bilin(const float* __restrict__ s0, const float* __restrict__ t0,
           const float* __restrict__ dis_emb, const int* __restrict__ dht,
           const int* __restrict__ dth, const float* __restrict__ Wb,
           const float* __restrict__ bb, float* __restrict__ out)
{
  __shared__ float sS[BI][33];
  __shared__ float sT[32][152];
  const int tid = threadIdx.x;
  const int bp0 = blockIdx.x*32;
  for (int f = tid; f < 32*BI; f += 256){
    int pp = f / BI, i = f % BI;
    int bp = bp0 + pp;
    float sv, tv;
    if (i < 128){ sv = s0[(size_t)bp*128 + i]; tv = t0[(size_t)bp*128 + i]; }
    else {
      sv = dis_emb[(size_t)dht[bp]*20 + (i-128)];
      tv = dis_emb[(size_t)dth[bp]*20 + (i-128)];
    }
    sS[i][pp] = sv; sT[pp][i] = tv;
  }
  __syncthreads();
  const int ppg = tid >> 5, jb = tid & 31;
  const int pp0 = ppg*4;
  const int k0 = blockIdx.y*49, kend = min(k0+49, RELK);
  for (int k = k0; k < kend; k++){
    const float* Wk = Wb + (size_t)k*BI*BI;
    float acc[4][5];
    #pragma unroll
    for (int a=0;a<4;a++) for (int b=0;b<5;b++) acc[a][b]=0.f;
    for (int i=0;i<BI;i++){
      float sv0 = sS[i][pp0], sv1 = sS[i][pp0+1], sv2 = sS[i][pp0+2], sv3 = sS[i][pp0+3];
      const float* wrow = Wk + i*BI;
      #pragma unroll
      for (int jj=0;jj<5;jj++){
        int j = jb + 32*jj;
        if (j < BI){
          float w = wrow[j];
          acc[0][jj] += sv0*w; acc[1][jj] += sv1*w; acc[2][jj] += sv2*w; acc[3][jj] += sv3*w;
        }
      }
    }
    float dot[4] = {0.f,0.f,0.f,0.f};
    #pragma unroll
    for (int jj=0;jj<5;jj++){
      int j = jb + 32*jj;
      if (j < BI){
        #pragma unroll
        for (int p4=0;p4<4;p4++) dot[p4] += acc[p4][jj]*sT[pp0+p4][j];
      }
    }
    #pragma unroll
    for (int p4=0;p4<4;p4++)
      for (int o=16;o;o>>=1) dot[p4] += __shfl_down(dot[p4], o, 32);
    if (jb == 0){
      #pragma unroll
      for (int p4=0;p4<4;p4++)
        out[(size_t)(bp0+pp0+p4)*RELK + k] = dot[p4] + bb[k];
    }
  }
}

// =========================================================== host launcher
extern "C" void kernel_launch(void* const* d_in, const int* in_sizes, int n_in,
                              void* d_out, int out_size, void* d_ws, size_t ws_size,
                              hipStream_t stream)
{
  (void)in_sizes; (void)n_in; (void)out_size; (void)ws_size;
  const int*   ctx_idx = (const int*)  d_in[0];
  const int*   pos     = (const int*)  d_in[1];
  const int*   nerI    = (const int*)  d_in[2];
  const float* h_map   = (const float*)d_in[5];
  const float* t_map   = (const float*)d_in[6];
  const int*   dht     = (const int*)  d_in[8];
  const int*   dth     = (const int*)  d_in[9];
  const float* wemb    = (const float*)d_in[10];
  const float* eemb    = (const float*)d_in[11];
  const float* nemb    = (const float*)d_in[12];
  const float* demb    = (const float*)d_in[13];
  const float* Wih0    = (const float*)d_in[14];
  const float* Whh0    = (const float*)d_in[15];
  const float* b0      = (const float*)d_in[16];
  const float* Wih1    = (const float*)d_in[17];
  const float* Whh1    = (const float*)d_in[18];
  const float* b1      = (const float*)d_in[19];
  const float* Wih2    = (const float*)d_in[20];
  const float* Whh2    = (const float*)d_in[21];
  const float* b2      = (const float*)d_in[22];
  const float* Wxi     = (const float*)d_in[23];
  const float* bxi     = (const float*)d_in[24];
  const float* Wout    = (const float*)d_in[25];
  const float* bout    = (const float*)d_in[26];
  const float* Wfin    = (const float*)d_in[27];
  const float* bfin    = (const float*)d_in[28];
  const float* Wre     = (const float*)d_in[29];
  const float* bre     = (const float*)d_in[30];
  const float* Wbili   = (const float*)d_in[31];
  const float* bbili   = (const float*)d_in[32];

  float* ws    = (float*)d_ws;
  float* sent  = ws;                    // [8][512][140]   573440
  float* Hh    = sent + 573440;         // [512][8][256]  1048576
  float* yh    = Hh + 1048576;          // [8][512][140]   573440
  float* s0b   = yh + 573440;           // [4096][128]     524288
  float* t0b   = s0b + 524288;          // [4096][128]     524288
  float* reads2= t0b + 524288;          // [2][8cp][8][4096]  524288
  float* h0g   = reads2 + 524288;       // [2][8cp][8][256]    32768
  float* h1g   = h0g + 32768;
  float* h2g   = h1g + 32768;
  float* c0g   = h2g + 32768;
  float* c1g   = c0g + 32768;
  float* c2g   = c1g + 32768;
  float* z0g   = c2g + 32768;           // [8cp][8][1024]      65536
  float* z1g   = z0g + 65536;
  float* z2g   = z1g + 65536;
  float* Hy    = z2g + 65536;           // [2][8cp][8][256]    32768
  float* xig   = Hy + 32768;            // [8][10299]          82392
  float* Mb    = xig + 82392;           // [8][32][512]       131072
  float* ug    = Mb + 131072;           // [8][32]
  float* wwg   = ug + 256;
  float* pg    = wwg + 256;
  float* wrg   = pg + 256;              // [8][8][32]
  float* Lg    = wrg + 2048;            // [8][32][32]
  float* barf  = Lg + 8192;             // flags 256*16 + genrep 256*16 = 8192 ints
  float* WA_T  = barf + 8192;           // [1024][4608]   4718592
  float* W1T   = WA_T + 4718592;        // [1024][512]     524288
  float* W2T   = W1T + 524288;          // [1024][512]     524288
  float* WXIT  = W2T + 524288;          // [10299][256]   2636544
  float* WYT   = WXIT + 2636544;        // [140][4352]     609280
  float* o256  = Hh;                    // alias: Hh dead after persist+gemm use
  float* ctxb  = sent;                  // alias: sent dead after persist
  int* flags  = (int*)barf;
  int* genrep = flags + 256*FSTR;

  size_t stateFloats = (size_t)(WA_T - reads2);
  hipMemsetAsync(reads2, 0, stateFloats*sizeof(float), stream);

  // one-time transposed/concatenated weight copies
  hipLaunchKernelGGL(k_tr, dim3(18432), dim3(256), 0, stream,
                     Wih0, Whh0, 1024, 4236, 256, 4608, (long long)4718592, WA_T);
  hipLaunchKernelGGL(k_tr, dim3(2048), dim3(256), 0, stream,
                     Wih1, Whh1, 1024, 256, 256, 512, (long long)524288, W1T);
  hipLaunchKernelGGL(k_tr, dim3(2048), dim3(256), 0, stream,
                     Wih2, Whh2, 1024, 256, 256, 512, (long long)524288, W2T);
  hipLaunchKernelGGL(k_tr, dim3(10299), dim3(256), 0, stream,
                     Wxi, Wxi, 10299, 256, 0, 256, (long long)2636544, WXIT);
  hipLaunchKernelGGL(k_tr, dim3(2380), dim3(256), 0, stream,
                     Wout, Wout, 140, 4352, 0, 4352, (long long)609280, WYT);

  hipLaunchKernelGGL(k_sent, dim3((573440+255)/256), dim3(256), 0, stream,
                     ctx_idx, pos, nerI, wemb, eemb, nemb, sent);

  hipFuncSetAttribute(reinterpret_cast<const void*>(dnc_persist),
                      hipFuncAttributeMaxDynamicSharedMemorySize, LDSB);

  hipLaunchKernelGGL(dnc_persist, dim3(NWG), dim3(TPB), LDSB, stream,
                     sent, WA_T, b0, W1T, b1, W2T, b2, WXIT, bxi, WYT, bout,
                     Hh, yh, Hy, reads2,
                     h0g, h1g, h2g, c0g, c1g, c2g, z0g, z1g, z2g, xig,
                     Mb, ug, wwg, pg, wrg, Lg, flags, genrep);

  // out = ys @ W_final + b_final          [4096,140]x[140,256]
  hipLaunchKernelGGL(gemm16, dim3(256,1), dim3(256), 0, stream,
                     4096, 256, 140, yh, (long long)0, 140, Wfin, (long long)0, 256,
                     o256, (long long)0, 256, bfin, 0);
  // ctx = relu(out @ W_re + b_re)         [4096,256]x[256,128]
  hipLaunchKernelGGL(gemm16, dim3(256,1), dim3(256), 0, stream,
                     4096, 128, 256, o256, (long long)0, 256, Wre, (long long)0, 128,
                     ctxb, (long long)0, 128, bre, 1);
  // s0 / t0 : per-batch [512,512]x[512,128]
  hipLaunchKernelGGL(gemm16, dim3(32,8), dim3(256), 0, stream,
                     512, 128, 512, h_map, (long long)(512*512), 512,
                     ctxb, (long long)(512*128), 128,
                     s0b, (long long)(512*128), 128, (const float*)nullptr, 0);
  hipLaunchKernelGGL(gemm16, dim3(32,8), dim3(256), 0, stream,
                     512, 128, 512, t_map, (long long)(512*512), 512,
                     ctxb, (long long)(512*128), 128,
                     t0b, (long long)(512*128), 128, (const float*)nullptr, 0);
  // bilinear head
  hipLaunchKernelGGL(bilin, dim3(128,2), dim3(256), 0, stream,
                     s0b, t0b, demb, dht, dth, Wbili, bbili, (float*)d_out);
}

// Round 7
// 90092.853 us; speedup vs baseline: 1.0811x; 1.0811x over previous
//
#include <hip/hip_runtime.h>
#include <math.h>

// ---- static dims ----
#define B8      8
#define LSEQ    512
#define NWG     256
#define TPB     512
#define RELK    97
#define BI      148
#define FSTR    16        // barrier flag stride (ints) = 64B

// LDS float offsets
#define oWA     0         // [288][64]   18432
#define oW1     18432     // [64][32]     2048
#define oW2     20480     // [64][32]     2048
#define oWX     22528     // [48][256]   12288
#define oWY     34816     // [68][35]     2380
#define oST     37196     // stage/scratch 3752
#define LDSF    40948
#define LDSB    (LDSF*4)  // 163792 B

__device__ __forceinline__ float sigf(float x){
  return (x >= 0.f) ? 1.f/(1.f + expf(-x)) : expf(x)/(1.f + expf(x));
}
__device__ __forceinline__ float spf(float x){
  return (x > 0.f) ? x + log1pf(expf(-x)) : log1pf(expf(x));
}
// agent-scope (L3-coherent) transfers for cross-wg data (verified r5/r6)
__device__ __forceinline__ float agld(const float* p){
  return __hip_atomic_load(p, __ATOMIC_RELAXED, __HIP_MEMORY_SCOPE_AGENT);
}
__device__ __forceinline__ void agst(float* p, float v){
  __hip_atomic_store(p, v, __ATOMIC_RELAXED, __HIP_MEMORY_SCOPE_AGENT);
}

// ---------------------------------------------------------------- sent gather
__global__ __launch_bounds__(256)
void k_sent(const int* __restrict__ cidx, const int* __restrict__ pos,
            const int* __restrict__ ner, const float* __restrict__ wemb,
            const float* __restrict__ eemb, const float* __restrict__ nemb,
            float* __restrict__ sent)
{
  int flat = blockIdx.x*256 + threadIdx.x;
  if (flat >= B8*LSEQ*140) return;
  int d = flat % 140; int bl = flat / 140;
  float v;
  if (d < 100)      v = wemb[(size_t)cidx[bl]*100 + d];
  else if (d < 120) v = eemb[(size_t)pos[bl]*20 + (d-100)];
  else              v = nemb[(size_t)ner[bl]*20 + (d-120)];
  sent[flat] = v;
}

// ------------------------------------------- weight transpose (once, WXI)
__global__ __launch_bounds__(256)
void k_tr(const float* __restrict__ A, const float* __restrict__ Bsrc,
          int N, int K1a, int K1b, int K2, long long total, float* __restrict__ T)
{
  long long i = (long long)blockIdx.x*256 + threadIdx.x;
  if (i >= total) return;
  int k = (int)(i % K2);
  long long c = i / K2;
  float v = 0.f;
  if (k < K1a)            v = A[(size_t)k*N + c];
  else if (k < K1a+K1b)   v = Bsrc[(size_t)(k-K1a)*N + c];
  T[i] = v;
}

// ---------------------------------------------------------- global barrier
__device__ __forceinline__ void gbar(int* flags, int* genrep, int seq){
  __syncthreads();
  const int tid = threadIdx.x;
  const int bid = blockIdx.x;
  if (tid == 0){
    asm volatile("s_waitcnt vmcnt(0)" ::: "memory");
    __hip_atomic_store(&flags[bid*FSTR], seq, __ATOMIC_RELAXED, __HIP_MEMORY_SCOPE_AGENT);
  }
  if (bid == 0){
    if (tid < NWG){
      while (__hip_atomic_load(&flags[tid*FSTR], __ATOMIC_RELAXED, __HIP_MEMORY_SCOPE_AGENT) < seq)
        __builtin_amdgcn_s_sleep(1);
    }
    __syncthreads();
    if (tid < NWG)
      __hip_atomic_store(&genrep[tid*FSTR], seq, __ATOMIC_RELAXED, __HIP_MEMORY_SCOPE_AGENT);
  } else if (tid == 0){
    while (__hip_atomic_load(&genrep[bid*FSTR], __ATOMIC_RELAXED, __HIP_MEMORY_SCOPE_AGENT) < seq)
      __builtin_amdgcn_s_sleep(1);
  }
  __syncthreads();
}

// ------------------------------------- per-sample DNC memory addressing phase
// scratch = 3712 floats inside the 3752-float stage region
__device__ void mem_phase(float* lds, const float* __restrict__ xi,
                          float* __restrict__ M, float* u_g, float* ww_g,
                          float* p_g, float* wr_g, float* L_g, float* rout)
{
  const int tid = threadIdx.x;
  float* mL  = lds;          // [32][32]
  float* mwr = lds+1024;     // [8][32]
  float* mwrn= lds+1280;
  float* mcr = lds+1536;
  float* mfw = lds+1792;
  float* mbw = lds+2048;
  float* PSI = lds+2304;
  float* UU  = lds+2336;
  float* US  = lds+2368;
  float* AA  = lds+2400;
  float* CW  = lds+2432;
  float* WWN = lds+2464;
  float* WWO = lds+2496;
  float* PP  = lds+2528;
  int*   mord= (int*)(lds+2560);   // 32 ints
  float* mh  = lds+2592;           // 32: rb[0..7] sf[8..15] sb[16..23] fg[24..31]
  float* mpi = lds+2624;           // [8][3]
  float* msc = lds+2648;           // 40 scratch scalars
  float* q1  = lds+2688;           // 512
  float* q2  = lds+3200;           // 512 (end 3712)

  if (tid < 8){
    mh[tid]    = 1.f + spf(agld(&xi[4096+tid]));
    mh[8+tid]  = 1.f + spf(agld(&xi[10283+tid]));
    mh[16+tid] = 1.f + spf(agld(&xi[10291+tid]));
    mh[24+tid] = sigf(agld(&xi[5641+tid]));
    float e0=agld(&xi[5651+3*tid]), e1=agld(&xi[5652+3*tid]), e2=agld(&xi[5653+3*tid]);
    float mx=fmaxf(e0,fmaxf(e1,e2));
    float x0=expf(e0-mx), x1=expf(e1-mx), x2=expf(e2-mx);
    float inv=1.f/(x0+x1+x2);
    mpi[tid*3]=x0*inv; mpi[tid*3+1]=x1*inv; mpi[tid*3+2]=x2*inv;
  }
  if (tid==0){ msc[0]=1.f+spf(agld(&xi[4616])); msc[1]=sigf(agld(&xi[5649])); msc[2]=sigf(agld(&xi[5650])); }
  if (tid<32){ UU[tid]=u_g[tid]; WWO[tid]=ww_g[tid]; PP[tid]=p_g[tid]; }
  if (tid<256) mwr[tid]=wr_g[tid];
  mL[tid]=L_g[tid]; mL[tid+512]=L_g[tid+512];
  { float wm = 0.1f+0.9f*sigf(agld(&xi[5675+tid])); q1[tid]=agld(&xi[4104+tid])*wm; q2[tid]=wm; }
  __syncthreads();

  if (tid<32){
    float psi=1.f;
    #pragma unroll
    for (int r=0;r<8;r++) psi *= (1.f - mh[24+r]*mwr[r*32+tid]);
    PSI[tid]=psi;
    float uo=UU[tid], wo=WWO[tid];
    UU[tid]=(uo+wo-uo*wo)*psi;
  }
  __syncthreads();
  if (tid<32){
    float un=UU[tid]; int rank=0;
    for (int m=0;m<32;m++){ float um=UU[m]; rank += (um<un)||(um==un && m<tid); }
    mord[rank]=tid;
  }
  __syncthreads();
  if (tid<32) US[tid]=UU[mord[tid]];
  __syncthreads();
  if (tid==0){ float cp=1.f; for (int j=0;j<32;j++){ AA[mord[j]]=(1.f-US[j])*cp; cp*=US[j]; } }
  __syncthreads();

  { float q=q1[tid]*q1[tid];
    for (int o=32;o;o>>=1) q += __shfl_down(q,o,64);
    if ((tid&63)==0) msc[8+(tid>>6)]=q; }
  __syncthreads();
  if (tid==0){ float q=0.f; for (int i=0;i<8;i++) q+=msc[8+i]; msc[3]=sqrtf(q); }
  __syncthreads();
  { int n=tid>>4, wsub=tid&15;
    float d=0.f,q=0.f;
    for (int i=0;i<32;i++){ int w=wsub+16*i; float m=M[(size_t)n*512+w]; float t2=m*q2[w]; d+=q1[w]*t2; q+=t2*t2; }
    for (int o=8;o;o>>=1){ d+=__shfl_down(d,o,16); q+=__shfl_down(q,o,16); }
    if (wsub==0){ float cs=d/(msc[3]*sqrtf(q)+1e-6f); CW[n]=msc[0]*cs; } }
  __syncthreads();
  if (tid==0){ float mx=-1e30f; for(int n=0;n<32;n++) mx=fmaxf(mx,CW[n]); msc[4]=mx; }
  __syncthreads();
  if (tid<32) CW[tid]=expf(CW[tid]-msc[4]);
  __syncthreads();
  if (tid==0){ float sm=0.f; for(int n=0;n<32;n++) sm+=CW[n]; msc[5]=1.f/sm; }
  __syncthreads();
  if (tid<32) CW[tid]*=msc[5];
  __syncthreads();
  if (tid<32) WWN[tid]=msc[2]*(msc[1]*AA[tid]+(1.f-msc[1])*CW[tid]);
  __syncthreads();
  { float er=sigf(agld(&xi[4617+tid])); float wv=agld(&xi[5129+tid]);
    for (int n=0;n<32;n++){ size_t idx=(size_t)n*512+tid; float m=M[idx];
      M[idx]=m*PSI[n]*(1.f-WWN[n]*er)+WWN[n]*wv; } }
  __syncthreads();
  for (int ii=0;ii<2;ii++){ int f=tid+512*ii; int i=f>>5, j=f&31;
    float nl=(1.f-WWN[i]-WWN[j])*mL[f]+WWN[i]*PP[j];
    mL[f]=(i==j)?0.f:nl; }
  __syncthreads();
  if (tid==0){ float sw=0.f; for(int n=0;n<32;n++) sw+=WWN[n]; msc[6]=sw; }
  __syncthreads();
  if (tid<32) PP[tid]=(1.f-msc[6])*PP[tid]+WWN[tid];
  __syncthreads();
  { int r=(tid>>5)&7, i=tid&31; bool isB=(tid>=256);
    float accv=0.f;
    if (!isB){ for (int j=0;j<32;j++) accv += mL[i*32+j]*mwr[r*32+j]; }
    else     { for (int j=0;j<32;j++) accv += mL[j*32+i]*mwr[r*32+j]; }
    float sp = isB? mh[16+r] : mh[8+r];
    float e = expf(sp*logf(accv+1e-6f));
    if (!isB) mfw[r*32+i]=e; else mbw[r*32+i]=e; }
  __syncthreads();
  if (tid<16){ int r=tid&7; float sm=0.f;
    if (tid<8){ for(int n=0;n<32;n++) sm+=mfw[r*32+n]; msc[16+r]=1.f/sm; }
    else      { for(int n=0;n<32;n++) sm+=mbw[r*32+n]; msc[24+r]=1.f/sm; } }
  __syncthreads();
  { int r=(tid>>5)&7, i=tid&31; bool isB=(tid>=256);
    if (!isB) mfw[r*32+i]*=msc[16+r]; else mbw[r*32+i]*=msc[24+r]; }
  __syncthreads();
  for (int r=0;r<8;r++){
    { float rm=0.1f+0.9f*sigf(agld(&xi[6187+r*512+tid]));
      q1[tid]=agld(&xi[r*512+tid])*rm; q2[tid]=rm; }
    __syncthreads();
    { float q=q1[tid]*q1[tid];
      for (int o=32;o;o>>=1) q+=__shfl_down(q,o,64);
      if ((tid&63)==0) msc[8+(tid>>6)]=q; }
    __syncthreads();
    if (tid==0){ float qq=0.f; for(int i=0;i<8;i++) qq+=msc[8+i]; msc[32]=sqrtf(qq); }
    __syncthreads();
    { int n=tid>>4, wsub=tid&15;
      float d=0.f,q=0.f;
      for (int i=0;i<32;i++){ int w=wsub+16*i; float m=M[(size_t)n*512+w]; float t2=m*q2[w]; d+=q1[w]*t2; q+=t2*t2; }
      for (int o=8;o;o>>=1){ d+=__shfl_down(d,o,16); q+=__shfl_down(q,o,16); }
      if (wsub==0){ float cs=d/(msc[32]*sqrtf(q)+1e-6f); mcr[r*32+n]=mh[r]*cs; } }
    __syncthreads();
  }
  if (tid<8){ int r=tid; float mx=-1e30f;
    for (int n=0;n<32;n++) mx=fmaxf(mx,mcr[r*32+n]);
    float sm=0.f;
    for (int n=0;n<32;n++){ float e=expf(mcr[r*32+n]-mx); mcr[r*32+n]=e; sm+=e; }
    float inv=1.f/sm;
    for (int n=0;n<32;n++) mcr[r*32+n]*=inv; }
  __syncthreads();
  if (tid<256){ int r=tid>>5, n=tid&31;
    float v=mpi[r*3]*mbw[r*32+n]+mpi[r*3+1]*mcr[r*32+n]+mpi[r*3+2]*mfw[r*32+n];
    mwrn[tid]=v; wr_g[tid]=v; }
  __syncthreads();
  { int r=tid>>6, wsub=tid&63;
    for (int i2=0;i2<8;i2++){ int w=wsub+64*i2;
      float accv=0.f;
      for (int n=0;n<32;n++) accv+=mwrn[r*32+n]*M[(size_t)n*512+w];
      agst(&rout[r*512+w], accv); } }
  if (tid<32){ u_g[tid]=UU[tid]; ww_g[tid]=WWN[tid]; p_g[tid]=PP[tid]; }
  L_g[tid]=mL[tid]; L_g[tid+512]=mL[tid+512];
}

// ---------------------------------------------- persistent whole-recurrence
__global__ __launch_bounds__(TPB, 1)
void dnc_persist(
  const float* __restrict__ sent,
  const float* __restrict__ Wih0, const float* __restrict__ Whh0, const float* __restrict__ b0,
  const float* __restrict__ Wih1, const float* __restrict__ Whh1, const float* __restrict__ b1,
  const float* __restrict__ Wih2, const float* __restrict__ Whh2, const float* __restrict__ b2,
  const float* __restrict__ WXIT, const float* __restrict__ bxi,
  const float* __restrict__ Wout, const float* __restrict__ bout,
  float* __restrict__ yh,
  float* __restrict__ reads,
  float* __restrict__ h0, float* __restrict__ h1,
  float* __restrict__ h2u, float* __restrict__ h2c,
  float* __restrict__ c0p, float* __restrict__ c1p, float* __restrict__ c2p,
  float* __restrict__ zp0, float* __restrict__ zp1, float* __restrict__ zp2,
  float* __restrict__ yp, float* __restrict__ xig,
  float* __restrict__ Mb, float* __restrict__ ug, float* __restrict__ wwg,
  float* __restrict__ pg, float* __restrict__ wrg, float* __restrict__ Lg,
  int* flags, int* genrep)
{
  extern __shared__ float lds[];
  const int wg  = blockIdx.x;
  const int tid = threadIdx.x;
  // decompositions
  const int cg  = wg >> 4, kg  = wg & 15;    // phase A: 64 cols, 288 k
  const int cgB = wg >> 3, kgB = wg & 7;     // phase B/C: 32 cols, 64 k
  const int ycg = wg >> 6, ykg = wg & 63;    // y: 35 cols, 68 k
  const int xc  = tid >> 6, xk = tid & 63;   // phase D layout (r6)
  float* stg = lds + oST;
  int seq = 0;

  // ---------------- one-time: weight slices -> LDS ----------------
  for (int f=tid; f<18432; f+=TPB){          // WA [kk][64cc]
    int kk=f>>6, cc=f&63;
    int gk=kg*288+kk, gc=cg*64+cc;
    float v=0.f;
    if (gk<4236) v=Wih0[(size_t)gk*1024+gc];
    else if (gk<4492) v=Whh0[(size_t)(gk-4236)*1024+gc];
    lds[oWA+f]=v;
  }
  for (int f=tid; f<2048; f+=TPB){           // W1 [kk][32cc]
    int kk=f>>5, cc=f&31;
    int gk=kgB*64+kk, gc=cgB*32+cc;
    lds[oW1+f] = (gk<256)? Wih1[(size_t)gk*1024+gc] : Whh1[(size_t)(gk-256)*1024+gc];
  }
  for (int f=tid; f<2048; f+=TPB){           // W2
    int kk=f>>5, cc=f&31;
    int gk=kgB*64+kk, gc=cgB*32+cc;
    lds[oW2+f] = (gk<256)? Wih2[(size_t)gk*1024+gc] : Whh2[(size_t)(gk-256)*1024+gc];
  }
  for (int f=tid; f<12288; f+=TPB){          // WXI [cl][256k] (r6 layout)
    int cl=f>>8, k=f&255; int col=wg*48+cl;
    lds[oWX+f] = (col<10299)? WXIT[(size_t)col*256+k] : 0.f;
  }
  for (int f=tid; f<2380; f+=TPB){           // WY [kk][35cc]
    int kk=f/35, cc=f%35;
    int gk=ykg*68+kk, gc=ycg*35+cc;          // gk<4352, gc<140 always
    lds[oWY+f] = Wout[(size_t)gk*140+gc];
  }
  __syncthreads();

  #pragma unroll 1
  for (int t=0; t<LSEQ; t++){
    // ========== phase A: z0 partial gemm + y(t-1) partial gemm ==========
    {
      float* sAct = stg;            // [8][288]
      float* sActY= stg+2304;       // [8][68]
      for (int f=tid; f<2304; f+=TPB){
        int s=f/288, kk=f%288; int g=kg*288+kk;
        float v;
        if (g<140)       v = sent[((size_t)s*512+t)*140+g];
        else if (g<4236) v = agld(&reads[s*4096+g-140]);
        else if (g<4492) v = agld(&h0[s*256+(g-4236)]);
        else             v = 0.f;
        sAct[f]=v;
      }
      if (t>0) for (int f=tid; f<544; f+=TPB){
        int s=f/68, kk=f%68; int gy=ykg*68+kk;
        sActY[f] = (gy<256)? agld(&h2c[s*256+gy]) : agld(&reads[s*4096+gy-256]);
      }
      __syncthreads();
      { int cc=tid&63, s=tid>>6;
        const float* wAl = lds+oWA;
        const float* ac  = sAct + s*288;
        float acc=0.f;
        #pragma unroll 8
        for (int kk=0; kk<288; kk++) acc += wAl[kk*64+cc]*ac[kk];
        agst(&zp0[(size_t)(kg*8+s)*1024 + cg*64+cc], acc); }
      if (t>0 && tid<280){ int s=tid/35, cc=tid%35;
        const float* wYl = lds+oWY;
        const float* ac  = sActY + s*68;
        float acc=0.f;
        #pragma unroll 4
        for (int kk=0; kk<68; kk++) acc += wYl[kk*35+cc]*ac[kk];
        agst(&yp[(size_t)(ykg*8+s)*144 + ycg*35+cc], acc); }
    }
    gbar(flags,genrep,++seq);

    // ========== phase A2: reduce z0 + cell0 -> h0 (wgs 0..63) ==========
    if (wg < 64){
      int s = wg>>3, part = wg&7;
      float* sP = stg;              // [4][128]
      { int j32=tid&31, q=(tid>>5)&3, kp=tid>>7;
        int col = q*256 + part*32 + j32;
        float v=0.f;
        for (int k2=kp*4; k2<kp*4+4; k2++) v += agld(&zp0[(size_t)(k2*8+s)*1024+col]);
        sP[kp*128 + q*32 + j32] = v; }
      __syncthreads();
      if (tid<32){
        int j = part*32 + tid;
        float zq[4];
        #pragma unroll
        for (int q=0;q<4;q++){ float v=0.f;
          for (int k2=0;k2<4;k2++) v += sP[k2*128+q*32+tid];
          zq[q]=v + b0[q*256+j]; }
        float cold=c0p[s*256+j];
        float cn=sigf(zq[1])*cold + sigf(zq[0])*tanhf(zq[2]);
        float h=sigf(zq[3])*tanhf(cn);
        c0p[s*256+j]=cn;
        agst(&h0[s*256+j], h);
      }
    }
    gbar(flags,genrep,++seq);

    // ========== phase B: z1 partial gemm ==========
    {
      float* sAct = stg;            // [8][64]
      for (int f=tid; f<512; f+=TPB){ int s=f>>6, kk=f&63; int g=kgB*64+kk;
        sAct[f] = (g<256)? agld(&h0[s*256+g]) : agld(&h1[s*256+g-256]); }
      __syncthreads();
      if (tid<256){ int cc=tid&31, s=tid>>5;
        const float* w1l = lds+oW1;
        const float* ac  = sAct + s*64;
        float acc=0.f;
        #pragma unroll 8
        for (int kk=0; kk<64; kk++) acc += w1l[kk*32+cc]*ac[kk];
        agst(&zp1[(size_t)(kgB*8+s)*1024 + cgB*32+cc], acc); }
    }
    gbar(flags,genrep,++seq);

    // ========== phase B2: reduce z1 + cell1 -> h1 ==========
    if (wg < 64){
      int s = wg>>3, part = wg&7;
      float* sP = stg;              // [2][128]
      if (tid<256){ int j32=tid&31, q=(tid>>5)&3, kp=tid>>7;
        int col = q*256 + part*32 + j32;
        float v=0.f;
        for (int k2=kp*4; k2<kp*4+4; k2++) v += agld(&zp1[(size_t)(k2*8+s)*1024+col]);
        sP[kp*128 + q*32 + j32] = v; }
      __syncthreads();
      if (tid<32){
        int j = part*32 + tid;
        float zq[4];
        #pragma unroll
        for (int q=0;q<4;q++) zq[q]=sP[q*32+tid]+sP[128+q*32+tid]+b1[q*256+j];
        float cold=c1p[s*256+j];
        float cn=sigf(zq[1])*cold + sigf(zq[0])*tanhf(zq[2]);
        float h=sigf(zq[3])*tanhf(cn);
        c1p[s*256+j]=cn;
        agst(&h1[s*256+j], h);
      }
    }
    gbar(flags,genrep,++seq);

    // ========== phase C: z2 partial gemm ==========
    {
      float* sAct = stg;
      for (int f=tid; f<512; f+=TPB){ int s=f>>6, kk=f&63; int g=kgB*64+kk;
        sAct[f] = (g<256)? agld(&h1[s*256+g]) : agld(&h2u[s*256+g-256]); }
      __syncthreads();
      if (tid<256){ int cc=tid&31, s=tid>>5;
        const float* w2l = lds+oW2;
        const float* ac  = sAct + s*64;
        float acc=0.f;
        #pragma unroll 8
        for (int kk=0; kk<64; kk++) acc += w2l[kk*32+cc]*ac[kk];
        agst(&zp2[(size_t)(kgB*8+s)*1024 + cgB*32+cc], acc); }
    }
    gbar(flags,genrep,++seq);

    // ========== phase C2: reduce z2 + cell2 -> h2u, h2c ==========
    if (wg < 64){
      int s = wg>>3, part = wg&7;
      float* sP = stg;
      if (tid<256){ int j32=tid&31, q=(tid>>5)&3, kp=tid>>7;
        int col = q*256 + part*32 + j32;
        float v=0.f;
        for (int k2=kp*4; k2<kp*4+4; k2++) v += agld(&zp2[(size_t)(k2*8+s)*1024+col]);
        sP[kp*128 + q*32 + j32] = v; }
      __syncthreads();
      if (tid<32){
        int j = part*32 + tid;
        float zq[4];
        #pragma unroll
        for (int q=0;q<4;q++) zq[q]=sP[q*32+tid]+sP[128+q*32+tid]+b2[q*256+j];
        float cold=c2p[s*256+j];
        float cn=sigf(zq[1])*cold + sigf(zq[0])*tanhf(zq[2]);
        float h2=sigf(zq[3])*tanhf(cn);
        float hc=fminf(fmaxf(h2,-20.f),20.f);
        c2p[s*256+j]=cn;
        agst(&h2u[s*256+j], h2);
        agst(&h2c[s*256+j], hc);
      }
    }
    gbar(flags,genrep,++seq);

    // ========== phase D: xi gemm (full K=256, 48 cols/wg) ==========
    {
      float* sA2 = stg;             // [8][260]
      for (int f=tid; f<2048; f+=TPB){ int s=f>>8, j=f&255;
        sA2[s*260+j] = agld(&h2c[s*256+j]); }
      __syncthreads();
      float accx[6][8];
      #pragma unroll
      for (int cc=0;cc<6;cc++)
        #pragma unroll
        for (int s=0;s<8;s++) accx[cc][s]=0.f;
      #pragma unroll
      for (int s=0;s<8;s++){
        float4 a = *reinterpret_cast<const float4*>(&sA2[s*260 + (xk<<2)]);
        #pragma unroll
        for (int cc=0;cc<6;cc++){
          float4 wv = *reinterpret_cast<const float4*>(&lds[oWX + (xc*6+cc)*256 + (xk<<2)]);
          accx[cc][s] += a.x*wv.x + a.y*wv.y + a.z*wv.z + a.w*wv.w;
        }
      }
      #pragma unroll
      for (int o=32;o;o>>=1)
        #pragma unroll
        for (int cc=0;cc<6;cc++)
          #pragma unroll
          for (int s=0;s<8;s++) accx[cc][s]+=__shfl_down(accx[cc][s],o,64);
      if ((tid&63)==0){
        #pragma unroll
        for (int cc=0;cc<6;cc++){
          int col = wg*48 + xc*6 + cc;
          if (col < 10299){
            #pragma unroll
            for (int s=0;s<8;s++) agst(&xig[(size_t)s*10299+col], accx[cc][s]+bxi[col]);
          }
        }
      }
    }
    gbar(flags,genrep,++seq);

    // ========== phase E: memory update (wg<8) + y(t-1) reduce ==========
    if (wg < 8){
      mem_phase(stg, xig + (size_t)wg*10299, Mb + (size_t)wg*16384,
                ug+wg*32, wwg+wg*32, pg+wg*32, wrg+wg*256, Lg+wg*1024,
                reads + wg*4096);
    } else if (wg < 148 && t > 0){
      int ty = t-1, j = wg-8;
      int s = tid>>6, kg2 = tid&63;
      float v = agld(&yp[(size_t)(kg2*8+s)*144 + j]);
      #pragma unroll
      for (int o=32;o;o>>=1) v += __shfl_down(v,o,64);
      if (kg2==0) yh[((size_t)s*512+ty)*140+j] = v + bout[j];
    }
    gbar(flags,genrep,++seq);
  }

  // ---------------- y(511): partials + reduce ----------------
  {
    float* sActY = stg;
    for (int f=tid; f<544; f+=TPB){
      int s=f/68, kk=f%68; int gy=ykg*68+kk;
      sActY[f] = (gy<256)? agld(&h2c[s*256+gy]) : agld(&reads[s*4096+gy-256]);
    }
    __syncthreads();
    if (tid<280){ int s=tid/35, cc=tid%35;
      const float* wYl = lds+oWY;
      const float* ac  = sActY + s*68;
      float acc=0.f;
      for (int kk=0; kk<68; kk++) acc += wYl[kk*35+cc]*ac[kk];
      agst(&yp[(size_t)(ykg*8+s)*144 + ycg*35+cc], acc); }
  }
  gbar(flags,genrep,++seq);
  if (wg>=8 && wg<148){
    int j = wg-8;
    int s = tid>>6, kg2 = tid&63;
    float v = agld(&yp[(size_t)(kg2*8+s)*144 + j]);
    #pragma unroll
    for (int o=32;o;o>>=1) v += __shfl_down(v,o,64);
    if (kg2==0) yh[((size_t)s*512+511)*140+j] = v + bout[j];
  }
}

// ---------------------------------------- generic 16-row tiled gemm (lda==K)
__global__ __launch_bounds__(256)
void gemm16(int M, int N, int K,
            const float* __restrict__ A, long long sAb, int lda,
            const float* __restrict__ Bm, long long sBb, int ldb,
            float* __restrict__ C, long long sCb, int ldc,
            const float* __restrict__ bias, int relu)
{
  __shared__ float sAh[16*512];
  const int tid = threadIdx.x;
  const float* Ab = A + (size_t)blockIdx.y*sAb;
  const float* Bb = Bm + (size_t)blockIdx.y*sBb;
  float* Cb = C + (size_t)blockIdx.y*sCb;
  const int m0 = blockIdx.x*16;
  const int tot = 16*K;
  for (int f = tid; f < tot; f += 256) sAh[f] = Ab[(size_t)m0*lda + f];
  __syncthreads();
  int c = (tid & 63)*4; int rg = tid >> 6;
  if (c >= N) return;
  float acc[4][4] = {};
  for (int k=0;k<K;k++){
    float4 bv = *reinterpret_cast<const float4*>(Bb + (size_t)k*ldb + c);
    #pragma unroll
    for (int rr=0;rr<4;rr++){
      float a = sAh[(rg*4+rr)*K + k];
      acc[rr][0] += a*bv.x; acc[rr][1] += a*bv.y; acc[rr][2] += a*bv.z; acc[rr][3] += a*bv.w;
    }
  }
  for (int rr=0;rr<4;rr++){
    int m = m0 + rg*4 + rr;
    #pragma unroll
    for (int e=0;e<4;e++){
      float v = acc[rr][e] + (bias ? bias[c+e] : 0.f);
      if (relu) v = fmaxf(v, 0.f);
      Cb[(size_t)m*ldc + c + e] = v;
    }
  }
}

// ------------------------------------------------------------ bilinear head
__global__ __launch_bounds__(256)
void bilin(const float* __restrict__ s0, const float* __restrict__ t0,
           const float* __restrict__ dis_emb, const int* __restrict__ dht,
           const int* __restrict__ dth, const float* __restrict__ Wb,
           const float* __restrict__ bb, float* __restrict__ out)
{
  __shared__ float sS[BI][33];
  __shared__ float sT[32][152];
  const int tid = threadIdx.x;
  const int bp0 = blockIdx.x*32;
  for (int f = tid; f < 32*BI; f += 256){
    int pp = f / BI, i = f % BI;
    int bp = bp0 + pp;
    float sv, tv;
    if (i < 128){ sv = s0[(size_t)bp*128 + i]; tv = t0[(size_t)bp*128 + i]; }
    else {
      sv = dis_emb[(size_t)dht[bp]*20 + (i-128)];
      tv = dis_emb[(size_t)dth[bp]*20 + (i-128)];
    }
    sS[i][pp] = sv; sT[pp][i] = tv;
  }
  __syncthreads();
  const int ppg = tid >> 5, jb = tid & 31;
  const int pp0 = ppg*4;
  const int k0 = blockIdx.y*49, kend = min(k0+49, RELK);
  for (int k = k0; k < kend; k++){
    const float* Wk = Wb + (size_t)k*BI*BI;
    float acc[4][5];
    #pragma unroll
    for (int a=0;a<4;a++) for (int b=0;b<5;b++) acc[a][b]=0.f;
    for (int i=0;i<BI;i++){
      float sv0 = sS[i][pp0], sv1 = sS[i][pp0+1], sv2 = sS[i][pp0+2], sv3 = sS[i][pp0+3];
      const float* wrow = Wk + i*BI;
      #pragma unroll
      for (int jj=0;jj<5;jj++){
        int j = jb + 32*jj;
        if (j < BI){
          float w = wrow[j];
          acc[0][jj] += sv0*w; acc[1][jj] += sv1*w; acc[2][jj] += sv2*w; acc[3][jj] += sv3*w;
        }
      }
    }
    float dot[4] = {0.f,0.f,0.f,0.f};
    #pragma unroll
    for (int jj=0;jj<5;jj++){
      int j = jb + 32*jj;
      if (j < BI){
        #pragma unroll
        for (int p4=0;p4<4;p4++) dot[p4] += acc[p4][jj]*sT[pp0+p4][j];
      }
    }
    #pragma unroll
    for (int p4=0;p4<4;p4++)
      for (int o=16;o;o>>=1) dot[p4] += __shfl_down(dot[p4], o, 32);
    if (jb == 0){
      #pragma unroll
      for (int p4=0;p4<4;p4++)
        out[(size_t)(bp0+pp0+p4)*RELK + k] = dot[p4] + bb[k];
    }
  }
}

// =========================================================== host launcher
extern "C" void kernel_launch(void* const* d_in, const int* in_sizes, int n_in,
                              void* d_out, int out_size, void* d_ws, size_t ws_size,
                              hipStream_t stream)
{
  (void)in_sizes; (void)n_in; (void)out_size; (void)ws_size;
  const int*   ctx_idx = (const int*)  d_in[0];
  const int*   pos     = (const int*)  d_in[1];
  const int*   nerI    = (const int*)  d_in[2];
  const float* h_map   = (const float*)d_in[5];
  const float* t_map   = (const float*)d_in[6];
  const int*   dht     = (const int*)  d_in[8];
  const int*   dth     = (const int*)  d_in[9];
  const float* wemb    = (const float*)d_in[10];
  const float* eemb    = (const float*)d_in[11];
  const float* nemb    = (const float*)d_in[12];
  const float* demb    = (const float*)d_in[13];
  const float* Wih0    = (const float*)d_in[14];
  const float* Whh0    = (const float*)d_in[15];
  const float* b0      = (const float*)d_in[16];
  const float* Wih1    = (const float*)d_in[17];
  const float* Whh1    = (const float*)d_in[18];
  const float* b1      = (const float*)d_in[19];
  const float* Wih2    = (const float*)d_in[20];
  const float* Whh2    = (const float*)d_in[21];
  const float* b2      = (const float*)d_in[22];
  const float* Wxi     = (const float*)d_in[23];
  const float* bxi     = (const float*)d_in[24];
  const float* Wout    = (const float*)d_in[25];
  const float* bout    = (const float*)d_in[26];
  const float* Wfin    = (const float*)d_in[27];
  const float* bfin    = (const float*)d_in[28];
  const float* Wre     = (const float*)d_in[29];
  const float* bre     = (const float*)d_in[30];
  const float* Wbili   = (const float*)d_in[31];
  const float* bbili   = (const float*)d_in[32];

  float* ws    = (float*)d_ws;
  float* sent  = ws;                    // 573440
  float* yh    = sent + 573440;         // 573440
  float* o256  = yh + 573440;           // 1048576
  float* s0b   = o256 + 1048576;        // 524288
  float* t0b   = s0b + 524288;          // 524288
  float* SB    = t0b + 524288;          // state base
  float* reads = SB + 0;                // 32768
  float* h0    = SB + 32768;            // 2048
  float* h1    = SB + 34816;
  float* h2u   = SB + 36864;
  float* h2c   = SB + 38912;
  float* c0p   = SB + 40960;
  float* c1p   = SB + 43008;
  float* c2p   = SB + 45056;
  float* zp0   = SB + 47104;            // 131072
  float* zp1   = SB + 178176;           // 65536
  float* zp2   = SB + 243712;           // 65536
  float* yp    = SB + 309248;           // 73728
  float* xig   = SB + 382976;           // 82392
  float* Mb    = SB + 465368;           // 131072
  float* ug    = SB + 596440;           // 256
  float* wwg   = SB + 596696;
  float* pg    = SB + 596952;
  float* wrg   = SB + 597208;           // 2048
  float* Lg    = SB + 599256;           // 8192
  float* barf  = SB + 607448;           // 8192 ints
  float* SEnd  = SB + 615640;
  float* WXIT  = SEnd;                  // 2636544
  float* ctxb  = yh;                    // alias: yh dead after gemm16 #1
  int* flags  = (int*)barf;
  int* genrep = flags + 256*FSTR;

  hipMemsetAsync(SB, 0, (size_t)615640*sizeof(float), stream);

  hipLaunchKernelGGL(k_tr, dim3(10299), dim3(256), 0, stream,
                     Wxi, Wxi, 10299, 256, 0, 256, (long long)2636544, WXIT);
  hipLaunchKernelGGL(k_sent, dim3((573440+255)/256), dim3(256), 0, stream,
                     ctx_idx, pos, nerI, wemb, eemb, nemb, sent);

  hipFuncSetAttribute(reinterpret_cast<const void*>(dnc_persist),
                      hipFuncAttributeMaxDynamicSharedMemorySize, LDSB);

  hipLaunchKernelGGL(dnc_persist, dim3(NWG), dim3(TPB), LDSB, stream,
                     sent, Wih0, Whh0, b0, Wih1, Whh1, b1, Wih2, Whh2, b2,
                     WXIT, bxi, Wout, bout, yh, reads,
                     h0, h1, h2u, h2c, c0p, c1p, c2p,
                     zp0, zp1, zp2, yp, xig,
                     Mb, ug, wwg, pg, wrg, Lg, flags, genrep);

  // out = ys @ W_final + b_final          [4096,140]x[140,256]
  hipLaunchKernelGGL(gemm16, dim3(256,1), dim3(256), 0, stream,
                     4096, 256, 140, yh, (long long)0, 140, Wfin, (long long)0, 256,
                     o256, (long long)0, 256, bfin, 0);
  // ctx = relu(out @ W_re + b_re)         [4096,256]x[256,128]
  hipLaunchKernelGGL(gemm16, dim3(256,1), dim3(256), 0, stream,
                     4096, 128, 256, o256, (long long)0, 256, Wre, (long long)0, 128,
                     ctxb, (long long)0, 128, bre, 1);
  // s0 / t0 : per-batch [512,512]x[512,128]
  hipLaunchKernelGGL(gemm16, dim3(32,8), dim3(256), 0, stream,
                     512, 128, 512, h_map, (long long)(512*512), 512,
                     ctxb, (long long)(512*128), 128,
                     s0b, (long long)(512*128), 128, (const float*)nullptr, 0);
  hipLaunchKernelGGL(gemm16, dim3(32,8), dim3(256), 0, stream,
                     512, 128, 512, t_map, (long long)(512*512), 512,
                     ctxb, (long long)(512*128), 128,
                     t0b, (long long)(512*128), 128, (const float*)nullptr, 0);
  // bilinear head
  hipLaunchKernelGGL(bilin, dim3(128,2), dim3(256), 0, stream,
                     s0b, t0b, demb, dht, dth, Wbili, bbili, (float*)d_out);
}